// Round 1
// baseline (1725.076 us; speedup 1.0000x reference)
//
#include <hip/hip_runtime.h>

#define N_NODES 100000
#define N_EDGES 1600000
#define D 64

// ws layout (floats): [0, N_NODES) = deg -> deg_inv_sqrt (in place)
//                     [AGG_OFF, AGG_OFF + N_NODES*D) = agg accumulator
#define AGG_OFF 100096  // 256B-aligned float offset (100096*4 = 400384)

__global__ void deg_kernel(const int* __restrict__ row, float* __restrict__ deg, int E) {
    int e = blockIdx.x * blockDim.x + threadIdx.x;
    if (e < E) atomicAdd(&deg[row[e]], 1.0f);
}

__global__ void dinv_kernel(float* __restrict__ deg, int N) {
    int i = blockIdx.x * blockDim.x + threadIdx.x;
    if (i < N) {
        float d = deg[i];
        deg[i] = (d > 0.0f) ? (1.0f / sqrtf(d)) : 0.0f;
    }
}

// One thread per (edge, 4-feature group): 16 threads per edge.
// Threads 0..15 of a wave handle edge e's 64 features as 16 float4 loads
// (coalesced within the group since x rows are contiguous).
__global__ void scatter_kernel(const int* __restrict__ row, const int* __restrict__ col,
                               const float* __restrict__ x, const float* __restrict__ dinv,
                               float* __restrict__ agg, int E) {
    int t = blockIdx.x * blockDim.x + threadIdx.x;
    int e = t >> 4;
    if (e >= E) return;
    int g = (t & 15) << 2;  // feature offset 0,4,...,60
    int src = col[e];
    int dst = row[e];
    float s = dinv[src];
    const float4 v = *(const float4*)(x + (size_t)src * D + g);
    float* a = agg + (size_t)dst * D + g;
    atomicAdd(a + 0, v.x * s);
    atomicAdd(a + 1, v.y * s);
    atomicAdd(a + 2, v.z * s);
    atomicAdd(a + 3, v.w * s);
}

// Epilogue: out[n][j] = relu(b[j] + sum_d (agg[n][d]*dinv[n]) * W[j][d])
// 256 threads/block = 4 nodes x 64 outputs. W staged transposed in LDS
// (Wt[d][j]) so the inner-loop read Wt[d*64 + j] is stride-1 across lanes
// (2 lanes/bank = free); arow[local][d] is a same-address broadcast (free).
__global__ __launch_bounds__(256) void mm_kernel(const float* __restrict__ agg,
                                                 const float* __restrict__ dinv,
                                                 const float* __restrict__ W,
                                                 const float* __restrict__ b,
                                                 float* __restrict__ out, int N) {
    __shared__ float Wt[D * D];
    __shared__ float arow[4][D];
    int tid = threadIdx.x;
    for (int i = tid; i < D * D; i += 256) {
        int j = i >> 6, d = i & 63;
        Wt[d * D + j] = W[i];
    }
    int local = tid >> 6;   // 0..3
    int j = tid & 63;
    int n = blockIdx.x * 4 + local;
    if (n < N) {
        float scale = dinv[n];
        arow[local][j] = agg[(size_t)n * D + j] * scale;
    }
    __syncthreads();
    if (n >= N) return;
    float acc = b[j];
#pragma unroll
    for (int d = 0; d < D; ++d)
        acc = fmaf(arow[local][d], Wt[d * D + j], acc);
    out[(size_t)n * D + j] = fmaxf(acc, 0.0f);
}

extern "C" void kernel_launch(void* const* d_in, const int* in_sizes, int n_in,
                              void* d_out, int out_size, void* d_ws, size_t ws_size,
                              hipStream_t stream) {
    const float* x    = (const float*)d_in[0];
    const int*   eidx = (const int*)d_in[1];
    const float* W    = (const float*)d_in[2];
    const float* b    = (const float*)d_in[3];
    float* out = (float*)d_out;
    float* ws  = (float*)d_ws;

    const int* row = eidx;
    const int* col = eidx + N_EDGES;
    float* deg = ws;               // becomes dinv in place
    float* agg = ws + AGG_OFF;

    // zero deg + agg (ws is poisoned 0xAA before every call)
    size_t zero_bytes = (size_t)(AGG_OFF + (size_t)N_NODES * D) * sizeof(float);
    hipMemsetAsync(d_ws, 0, zero_bytes, stream);

    {
        int blocks = (N_EDGES + 255) / 256;
        deg_kernel<<<blocks, 256, 0, stream>>>(row, deg, N_EDGES);
    }
    {
        int blocks = (N_NODES + 255) / 256;
        dinv_kernel<<<blocks, 256, 0, stream>>>(deg, N_NODES);
    }
    {
        long long threads = (long long)N_EDGES * 16;
        int blocks = (int)((threads + 255) / 256);
        scatter_kernel<<<blocks, 256, 0, stream>>>(row, col, x, deg, agg, N_EDGES);
    }
    {
        int blocks = (N_NODES + 3) / 4;
        mm_kernel<<<blocks, 256, 0, stream>>>(agg, deg, W, b, out, N_NODES);
    }
}

// Round 2
// 460.087 us; speedup vs baseline: 3.7495x; 3.7495x over previous
//
#include <hip/hip_runtime.h>

#define N_NODES 100000
#define N_EDGES 1600000
#define D 64
#define SCAN_B 1024
#define NB 98  // ceil(100000/1024)

// ws layout in 4-byte units:
#define DEG_OFF    0        // int[100000]  node in-degree (as destination)
#define DINV_OFF   100096   // float[100000] deg^-0.5
#define ROWPTR_OFF 200192   // int[100001]  CSR row pointers (by destination)
#define CURSOR_OFF 300544   // int[100000]  fill cursors (clobbered)
#define BSUM_OFF   400640   // int[128]     scan block sums
#define SCOL_OFF   400768   // int[1600000] edge sources, grouped by destination
#define Y_OFF      2000768  // float[100000*64] y = dinv .* (x @ W^T)

__global__ void deg_kernel(const int* __restrict__ row, int* __restrict__ deg, int E) {
    int e = blockIdx.x * blockDim.x + threadIdx.x;
    if (e < E) atomicAdd(&deg[row[e]], 1);
}

__global__ void dinv_kernel(const int* __restrict__ deg, float* __restrict__ dinv, int N) {
    int i = blockIdx.x * blockDim.x + threadIdx.x;
    if (i < N) {
        float d = (float)deg[i];
        dinv[i] = (d > 0.0f) ? (1.0f / sqrtf(d)) : 0.0f;
    }
}

// y[n][j] = dinv[n] * sum_d x[n][d] * W[j][d]
// 256 threads = 4 node-groups x 64 outputs; each group strides over 4 nodes
// -> 16 nodes/block, W staged once (amortized).
__global__ __launch_bounds__(256) void transform_kernel(
        const float* __restrict__ x, const float* __restrict__ dinv,
        const float* __restrict__ W, float* __restrict__ y, int N) {
    __shared__ float Wt[D * D];     // Wt[d][j] = W[j][d]
    __shared__ float xr[16][D];
    int tid = threadIdx.x;
    for (int i = tid; i < D * D; i += 256) {
        int j = i >> 6, d = i & 63;
        Wt[d * D + j] = W[i];
    }
    int grp = tid >> 6;   // 0..3
    int j = tid & 63;
    int nbase = blockIdx.x * 16;
    for (int s = 0; s < 4; ++s) {
        int n = nbase + grp * 4 + s;
        if (n < N) xr[grp * 4 + s][j] = x[(size_t)n * D + j];
    }
    __syncthreads();
    for (int s = 0; s < 4; ++s) {
        int n = nbase + grp * 4 + s;
        if (n >= N) break;
        float acc = 0.0f;
        const float* xrow = xr[grp * 4 + s];
#pragma unroll
        for (int d = 0; d < D; ++d)
            acc = fmaf(xrow[d], Wt[d * D + j], acc);
        y[(size_t)n * D + j] = acc * dinv[n];
    }
}

// ---- 3-kernel exclusive scan of deg -> row_ptr ----
__global__ __launch_bounds__(SCAN_B) void scan_blocks_kernel(
        const int* __restrict__ deg, int* __restrict__ row_ptr,
        int* __restrict__ bsum, int N) {
    __shared__ int s[SCAN_B];
    int t = threadIdx.x;
    int i = blockIdx.x * SCAN_B + t;
    int v = (i < N) ? deg[i] : 0;
    s[t] = v;
    __syncthreads();
    for (int off = 1; off < SCAN_B; off <<= 1) {
        int tmp = (t >= off) ? s[t - off] : 0;
        __syncthreads();
        s[t] += tmp;
        __syncthreads();
    }
    if (i < N) row_ptr[i + 1] = s[t];           // block-local inclusive
    if (t == SCAN_B - 1) bsum[blockIdx.x] = s[t];
}

__global__ void scan_totals_kernel(int* __restrict__ bsum, int nb) {
    if (threadIdx.x == 0 && blockIdx.x == 0) {
        int run = 0;
        for (int b = 0; b < nb; ++b) {
            int v = bsum[b];
            bsum[b] = run;
            run += v;
        }
    }
}

__global__ __launch_bounds__(SCAN_B) void scan_fixup_kernel(
        int* __restrict__ row_ptr, int* __restrict__ cursor,
        const int* __restrict__ bsum, int N) {
    int t = threadIdx.x;
    int i = blockIdx.x * SCAN_B + t;
    if (i < N) {
        int val = row_ptr[i + 1] + bsum[blockIdx.x];
        row_ptr[i + 1] = val;
        if (i + 1 < N) cursor[i + 1] = val;
    }
    if (i == 0) { row_ptr[0] = 0; cursor[0] = 0; }
}

// Bin each edge's source into its destination's CSR segment.
__global__ void bin_kernel(const int* __restrict__ row, const int* __restrict__ col,
                           int* __restrict__ cursor, int* __restrict__ scol, int E) {
    int e = blockIdx.x * blockDim.x + threadIdx.x;
    if (e < E) {
        int pos = atomicAdd(&cursor[row[e]], 1);
        scol[pos] = col[e];
    }
}

// One wave per node: acc[j] = sum over edges of y[src][j]; out = relu(dinv*acc + b).
__global__ __launch_bounds__(256) void gather_out_kernel(
        const float* __restrict__ y, const int* __restrict__ row_ptr,
        const int* __restrict__ scol, const float* __restrict__ dinv,
        const float* __restrict__ b, float* __restrict__ out, int N) {
    int tid = threadIdx.x;
    int wave = tid >> 6;          // 0..3
    int j = tid & 63;
    int n = blockIdx.x * 4 + wave;
    if (n >= N) return;
    int beg = row_ptr[n], end = row_ptr[n + 1];
    float acc0 = 0.0f, acc1 = 0.0f;
    int k = beg;
    for (; k + 1 < end; k += 2) {
        int c0 = scol[k], c1 = scol[k + 1];
        acc0 += y[(size_t)c0 * D + j];
        acc1 += y[(size_t)c1 * D + j];
    }
    if (k < end) acc0 += y[(size_t)scol[k] * D + j];
    float r = fmaf(dinv[n], acc0 + acc1, b[j]);
    out[(size_t)n * D + j] = fmaxf(r, 0.0f);
}

extern "C" void kernel_launch(void* const* d_in, const int* in_sizes, int n_in,
                              void* d_out, int out_size, void* d_ws, size_t ws_size,
                              hipStream_t stream) {
    const float* x    = (const float*)d_in[0];
    const int*   eidx = (const int*)d_in[1];
    const float* W    = (const float*)d_in[2];
    const float* b    = (const float*)d_in[3];
    float* out = (float*)d_out;
    char* ws = (char*)d_ws;

    const int* row = eidx;
    const int* col = eidx + N_EDGES;

    int*   deg     = (int*)  (ws + (size_t)DEG_OFF * 4);
    float* dinv    = (float*)(ws + (size_t)DINV_OFF * 4);
    int*   row_ptr = (int*)  (ws + (size_t)ROWPTR_OFF * 4);
    int*   cursor  = (int*)  (ws + (size_t)CURSOR_OFF * 4);
    int*   bsum    = (int*)  (ws + (size_t)BSUM_OFF * 4);
    int*   scol    = (int*)  (ws + (size_t)SCOL_OFF * 4);
    float* y       = (float*)(ws + (size_t)Y_OFF * 4);

    // only deg needs zeroing (ws is re-poisoned 0xAA every call)
    hipMemsetAsync(deg, 0, (size_t)N_NODES * sizeof(int), stream);

    deg_kernel<<<(N_EDGES + 255) / 256, 256, 0, stream>>>(row, deg, N_EDGES);
    dinv_kernel<<<(N_NODES + 255) / 256, 256, 0, stream>>>(deg, dinv, N_NODES);
    transform_kernel<<<(N_NODES + 15) / 16, 256, 0, stream>>>(x, dinv, W, y, N_NODES);
    scan_blocks_kernel<<<NB, SCAN_B, 0, stream>>>(deg, row_ptr, bsum, N_NODES);
    scan_totals_kernel<<<1, 64, 0, stream>>>(bsum, NB);
    scan_fixup_kernel<<<NB, SCAN_B, 0, stream>>>(row_ptr, cursor, bsum, N_NODES);
    bin_kernel<<<(N_EDGES + 255) / 256, 256, 0, stream>>>(row, col, cursor, scol, N_EDGES);
    gather_out_kernel<<<(N_NODES + 3) / 4, 256, 0, stream>>>(y, row_ptr, scol, dinv, b, out, N_NODES);
}

// Round 3
// 294.276 us; speedup vs baseline: 5.8621x; 1.5635x over previous
//
#include <hip/hip_runtime.h>

#define N_NODES 100000
#define N_EDGES 1600000
#define D 64

#define BSHIFT 7                 // 128 nodes per bucket
#define BNODES 128
#define NBUCKET 782              // ceil(100000/128)
#define CAP 3072                 // max edges per bucket (mean 2048, sigma ~45)
#define CHUNK 4096               // edges per pass1b block
#define NCHUNK 391               // ceil(1600000/4096)

// ws layout (bytes)
#define BCNT_OFF   0             // int[NBUCKET]   bucket edge counts (memset 0)
#define BPTR_OFF   4096          // int[NBUCKET+1] bucket offsets
#define BCUR_OFF   8192          // int[NBUCKET]   bucket fill cursors
#define DINV_OFF   12288         // float[N_NODES]
#define PAIRS_OFF  413696        // int2[N_EDGES]  (row,col) grouped by bucket
#define Y_OFF      13215744      // ushort[N_NODES*D]  y = dinv .* (x@W^T), bf16

__device__ __forceinline__ float bf2f(unsigned short u) {
    return __uint_as_float(((unsigned)u) << 16);
}
__device__ __forceinline__ unsigned short f2bf(float f) {
    unsigned bits = __float_as_uint(f);
    return (unsigned short)((bits + 0x7FFFu + ((bits >> 16) & 1u)) >> 16);
}

// Pass 1a: bucket histogram, LDS-privatized.
__global__ __launch_bounds__(256) void hist_kernel(const int* __restrict__ row,
                                                   int* __restrict__ bcnt) {
    __shared__ int h[NBUCKET];
    int t = threadIdx.x;
    for (int i = t; i < NBUCKET; i += 256) h[i] = 0;
    __syncthreads();
    int stride = gridDim.x * 256;
    for (int e = blockIdx.x * 256 + t; e < N_EDGES; e += stride)
        atomicAdd(&h[row[e] >> BSHIFT], 1);
    __syncthreads();
    for (int i = t; i < NBUCKET; i += 256) {
        int v = h[i];
        if (v) atomicAdd(&bcnt[i], v);
    }
}

// Exclusive scan over NBUCKET (single block, Hillis-Steele in LDS).
__global__ __launch_bounds__(1024) void scanb_kernel(const int* __restrict__ bcnt,
                                                     int* __restrict__ bptr,
                                                     int* __restrict__ bcur) {
    __shared__ int s[1024];
    int t = threadIdx.x;
    int v = (t < NBUCKET) ? bcnt[t] : 0;
    s[t] = v;
    __syncthreads();
    for (int off = 1; off < 1024; off <<= 1) {
        int tmp = (t >= off) ? s[t - off] : 0;
        __syncthreads();
        s[t] += tmp;
        __syncthreads();
    }
    if (t < NBUCKET) {
        int excl = s[t] - v;
        bptr[t] = excl;
        bcur[t] = excl;
        if (t == NBUCKET - 1) bptr[NBUCKET] = s[t];
    }
}

// Pass 1b: scatter (row,col) pairs into bucket regions, block-privatized
// cursors so writes to each bucket are appended in ~contiguous runs.
__global__ __launch_bounds__(256) void scat_kernel(const int* __restrict__ row,
                                                   const int* __restrict__ col,
                                                   int* __restrict__ bcur,
                                                   int2* __restrict__ pairs) {
    __shared__ int lcnt[NBUCKET];
    __shared__ int lbase[NBUCKET];
    __shared__ unsigned short lpos[CHUNK];
    int t = threadIdx.x;
    int base = blockIdx.x * CHUNK;
    for (int i = t; i < NBUCKET; i += 256) lcnt[i] = 0;
    __syncthreads();
#pragma unroll
    for (int i = 0; i < CHUNK / 256; ++i) {
        int e = base + i * 256 + t;
        if (e < N_EDGES)
            lpos[i * 256 + t] = (unsigned short)atomicAdd(&lcnt[row[e] >> BSHIFT], 1);
    }
    __syncthreads();
    for (int i = t; i < NBUCKET; i += 256) {
        int c = lcnt[i];
        if (c) lbase[i] = atomicAdd(&bcur[i], c);
    }
    __syncthreads();
#pragma unroll
    for (int i = 0; i < CHUNK / 256; ++i) {
        int e = base + i * 256 + t;
        if (e < N_EDGES) {
            int r = row[e], c = col[e];
            int b = r >> BSHIFT;
            pairs[lbase[b] + (int)lpos[i * 256 + t]] = make_int2(r, c);
        }
    }
}

// Per-bucket degree -> dinv (non-atomic global write; each node in 1 bucket).
__global__ __launch_bounds__(256) void degdinv_kernel(const int2* __restrict__ pairs,
                                                      const int* __restrict__ bptr,
                                                      float* __restrict__ dinv) {
    __shared__ int cnt[BNODES];
    int t = threadIdx.x;
    int b = blockIdx.x;
    if (t < BNODES) cnt[t] = 0;
    __syncthreads();
    int beg = bptr[b], end = bptr[b + 1];
    for (int k = beg + t; k < end; k += 256)
        atomicAdd(&cnt[pairs[k].x & (BNODES - 1)], 1);
    __syncthreads();
    if (t < BNODES) {
        int n = (b << BSHIFT) + t;
        if (n < N_NODES) {
            int d = cnt[t];
            dinv[n] = (d > 0) ? rsqrtf((float)d) : 0.0f;
        }
    }
}

// y[n][j] = bf16( dinv[n] * sum_d x[n][d] * W[j][d] )
__global__ __launch_bounds__(256) void transform_kernel(
        const float* __restrict__ x, const float* __restrict__ dinv,
        const float* __restrict__ W, unsigned short* __restrict__ y, int N) {
    __shared__ float Wt[D * D];
    __shared__ float xr[16][D];
    int tid = threadIdx.x;
    for (int i = tid; i < D * D; i += 256) {
        int j = i >> 6, d = i & 63;
        Wt[d * D + j] = W[i];
    }
    int grp = tid >> 6;
    int j = tid & 63;
    int nbase = blockIdx.x * 16;
    for (int s = 0; s < 4; ++s) {
        int n = nbase + grp * 4 + s;
        if (n < N) xr[grp * 4 + s][j] = x[(size_t)n * D + j];
    }
    __syncthreads();
    for (int s = 0; s < 4; ++s) {
        int n = nbase + grp * 4 + s;
        if (n >= N) break;
        float acc = 0.0f;
        const float* xrow = xr[grp * 4 + s];
#pragma unroll
        for (int d = 0; d < D; ++d)
            acc = fmaf(xrow[d], Wt[d * D + j], acc);
        y[(size_t)n * D + j] = f2bf(acc * dinv[n]);
    }
}

// Per-bucket: LDS histogram -> LDS scan -> LDS fine-bin -> per-node gather +
// bias + relu. One wave per node iteration; lane j = feature j.
__global__ __launch_bounds__(256) void mega_kernel(
        const int2* __restrict__ pairs, const int* __restrict__ bptr,
        const unsigned short* __restrict__ y, const float* __restrict__ dinv,
        const float* __restrict__ bias, float* __restrict__ out) {
    __shared__ int hist[BNODES];
    __shared__ int sc[BNODES];
    __shared__ int lrptr[BNODES + 1];
    __shared__ int lcur[BNODES];
    __shared__ int lds_scol[CAP];
    int t = threadIdx.x;
    int b = blockIdx.x;
    int beg = bptr[b], end = bptr[b + 1];
    if (t < BNODES) hist[t] = 0;
    __syncthreads();
    // A: histogram
    for (int k = beg + t; k < end; k += 256)
        atomicAdd(&hist[pairs[k].x & (BNODES - 1)], 1);
    __syncthreads();
    // B: inclusive scan over 128
    if (t < BNODES) sc[t] = hist[t];
    __syncthreads();
    for (int off = 1; off < BNODES; off <<= 1) {
        int v = (t < BNODES && t >= off) ? sc[t - off] : 0;
        __syncthreads();
        if (t < BNODES) sc[t] += v;
        __syncthreads();
    }
    if (t < BNODES) {
        lrptr[t + 1] = sc[t];
        lcur[t] = sc[t] - hist[t];   // exclusive start
    }
    if (t == 0) lrptr[0] = 0;
    __syncthreads();
    // C: fine bin into LDS
    for (int k = beg + t; k < end; k += 256) {
        int2 p = pairs[k];
        int pos = atomicAdd(&lcur[p.x & (BNODES - 1)], 1);
        if (pos < CAP) lds_scol[pos] = p.y;
    }
    __syncthreads();
    // D: per-node gather-accumulate, one wave per node
    int wave = t >> 6;
    int j = t & 63;
    float bj = bias[j];
    for (int ln = wave; ln < BNODES; ln += 4) {
        int n = (b << BSHIFT) + ln;
        if (n >= N_NODES) break;
        int s = lrptr[ln], e2 = lrptr[ln + 1];
        float a0 = 0.0f, a1 = 0.0f, a2 = 0.0f, a3 = 0.0f;
        int k = s;
        for (; k + 3 < e2; k += 4) {
            int c0 = lds_scol[k], c1 = lds_scol[k + 1];
            int c2 = lds_scol[k + 2], c3 = lds_scol[k + 3];
            a0 += bf2f(y[(size_t)c0 * D + j]);
            a1 += bf2f(y[(size_t)c1 * D + j]);
            a2 += bf2f(y[(size_t)c2 * D + j]);
            a3 += bf2f(y[(size_t)c3 * D + j]);
        }
        for (; k < e2; ++k) a0 += bf2f(y[(size_t)lds_scol[k] * D + j]);
        float r = fmaf(dinv[n], (a0 + a1) + (a2 + a3), bj);
        out[(size_t)n * D + j] = fmaxf(r, 0.0f);
    }
}

extern "C" void kernel_launch(void* const* d_in, const int* in_sizes, int n_in,
                              void* d_out, int out_size, void* d_ws, size_t ws_size,
                              hipStream_t stream) {
    const float* x    = (const float*)d_in[0];
    const int*   eidx = (const int*)d_in[1];
    const float* W    = (const float*)d_in[2];
    const float* b    = (const float*)d_in[3];
    float* out = (float*)d_out;
    char* ws = (char*)d_ws;

    const int* row = eidx;
    const int* col = eidx + N_EDGES;

    int*   bcnt  = (int*)  (ws + BCNT_OFF);
    int*   bptr  = (int*)  (ws + BPTR_OFF);
    int*   bcur  = (int*)  (ws + BCUR_OFF);
    float* dinv  = (float*)(ws + DINV_OFF);
    int2*  pairs = (int2*) (ws + PAIRS_OFF);
    unsigned short* y = (unsigned short*)(ws + Y_OFF);

    hipMemsetAsync(bcnt, 0, NBUCKET * sizeof(int), stream);

    hist_kernel<<<256, 256, 0, stream>>>(row, bcnt);
    scanb_kernel<<<1, 1024, 0, stream>>>(bcnt, bptr, bcur);
    scat_kernel<<<NCHUNK, 256, 0, stream>>>(row, col, bcur, pairs);
    degdinv_kernel<<<NBUCKET, 256, 0, stream>>>(pairs, bptr, dinv);
    transform_kernel<<<(N_NODES + 15) / 16, 256, 0, stream>>>(x, dinv, W, y, N_NODES);
    mega_kernel<<<NBUCKET, 256, 0, stream>>>(pairs, bptr, y, dinv, b, out);
}

// Round 4
// 185.463 us; speedup vs baseline: 9.3015x; 1.5867x over previous
//
#include <hip/hip_runtime.h>

#define N_NODES 100000
#define N_EDGES 1600000
#define D 64

#define BSHIFT 6                 // 64 nodes per bucket
#define BNODES 64
#define NBUCKET 1563             // ceil(100000/64)
#define CAP 1408                 // static per-bucket capacity (mean 1024, +12 sigma)
#define CHUNK 4096               // edges per scat block
#define EPT 16                   // edges per thread in scat
#define NCHUNK 391               // ceil(1600000/4096)
#define COLBITS 17
#define COLMASK 0x1FFFF

// ws layout (bytes)
#define BCUR_OFF  0              // int[NBUCKET] fill cursors (init to b*CAP)
#define PAIRS_OFF 8192           // int[NBUCKET*CAP] packed (rlocal<<17 | col)
#define Y_OFF     8811008        // ushort[N_NODES*D] y = dinv .* (x@W^T), bf16

__device__ __forceinline__ float bf2f(unsigned short u) {
    return __uint_as_float(((unsigned)u) << 16);
}
__device__ __forceinline__ unsigned f2bf(float f) {
    unsigned bits = __float_as_uint(f);
    return (bits + 0x7FFFu + ((bits >> 16) & 1u)) >> 16;
}

__global__ void initcur_kernel(int* __restrict__ bcur) {
    int i = blockIdx.x * blockDim.x + threadIdx.x;
    if (i < NBUCKET) bcur[i] = i * CAP;
}

// Bucket edges by destination>>6; write packed (rlocal<<17|col), appended
// per-bucket via block-privatized LDS counters + one global reservation.
__global__ __launch_bounds__(256) void scat_kernel(const int* __restrict__ row,
                                                   const int* __restrict__ col,
                                                   int* __restrict__ bcur,
                                                   int* __restrict__ pairs) {
    __shared__ int lcnt[NBUCKET];
    int t = threadIdx.x;
    int base = blockIdx.x * CHUNK;
    for (int i = t; i < NBUCKET; i += 256) lcnt[i] = 0;
    __syncthreads();
    int r[EPT], c[EPT], pos[EPT];
#pragma unroll
    for (int i = 0; i < EPT; ++i) {
        int e = base + i * 256 + t;
        if (e < N_EDGES) {
            r[i] = row[e];
            c[i] = col[e];
            pos[i] = atomicAdd(&lcnt[r[i] >> BSHIFT], 1);
        } else r[i] = -1;
    }
    __syncthreads();
    // reserve global space; overwrite lcnt[i] (owned by this thread) with base
    for (int i = t; i < NBUCKET; i += 256) {
        int cc = lcnt[i];
        if (cc) lcnt[i] = atomicAdd(&bcur[i], cc);
    }
    __syncthreads();
#pragma unroll
    for (int i = 0; i < EPT; ++i) {
        if (r[i] >= 0) {
            int b = r[i] >> BSHIFT;
            int rl = r[i] & (BNODES - 1);
            pairs[lcnt[b] + pos[i]] = (rl << COLBITS) | c[i];
        }
    }
}

// Per-bucket fused: degree hist -> dinv -> y[n] = bf16(dinv[n] * x[n] @ W^T).
// 4x4 register tiles, XT/WT staged d-major in LDS, float4 reads.
__global__ __launch_bounds__(256) void xform_kernel(
        const float* __restrict__ x, const float* __restrict__ W,
        const int* __restrict__ pairs, const int* __restrict__ bcur,
        unsigned short* __restrict__ y) {
    __shared__ __align__(16) float XT[D * 68];   // XT[d*68 + n]
    __shared__ __align__(16) float WT[D * 68];   // WT[d*68 + j]
    __shared__ int hist[BNODES];
    __shared__ float dl[BNODES];
    int t = threadIdx.x;
    int b = blockIdx.x;
    int nb0 = b << BSHIFT;
    // WT: coalesced W read (lanes -> d), transposed LDS write
    for (int i = t; i < D * D; i += 256) {
        int j = i >> 6, d = i & 63;
        WT[d * 68 + j] = W[i];
    }
    if (t < BNODES) hist[t] = 0;
    __syncthreads();
    // XT: coalesced x read (lanes -> d), transposed LDS write
    for (int i = t; i < BNODES * D; i += 256) {
        int n = i >> 6, d = i & 63;
        int g = nb0 + n;
        XT[d * 68 + n] = (g < N_NODES) ? x[(size_t)g * D + d] : 0.0f;
    }
    int beg = b * CAP, end = bcur[b];
    for (int k = beg + t; k < end; k += 256)
        atomicAdd(&hist[pairs[k] >> COLBITS], 1);
    __syncthreads();
    if (t < BNODES) dl[t] = (hist[t] > 0) ? rsqrtf((float)hist[t]) : 0.0f;
    __syncthreads();
    int tj = t & 15, tn = t >> 4;    // 16 j-tiles x 16 n-tiles
    float4 a0 = {0,0,0,0}, a1 = {0,0,0,0}, a2 = {0,0,0,0}, a3 = {0,0,0,0};
#pragma unroll 8
    for (int d = 0; d < D; ++d) {
        float4 xv = *(const float4*)&XT[d * 68 + tn * 4];
        float4 wv = *(const float4*)&WT[d * 68 + tj * 4];
        a0.x = fmaf(xv.x, wv.x, a0.x); a0.y = fmaf(xv.x, wv.y, a0.y);
        a0.z = fmaf(xv.x, wv.z, a0.z); a0.w = fmaf(xv.x, wv.w, a0.w);
        a1.x = fmaf(xv.y, wv.x, a1.x); a1.y = fmaf(xv.y, wv.y, a1.y);
        a1.z = fmaf(xv.y, wv.z, a1.z); a1.w = fmaf(xv.y, wv.w, a1.w);
        a2.x = fmaf(xv.z, wv.x, a2.x); a2.y = fmaf(xv.z, wv.y, a2.y);
        a2.z = fmaf(xv.z, wv.z, a2.z); a2.w = fmaf(xv.z, wv.w, a2.w);
        a3.x = fmaf(xv.w, wv.x, a3.x); a3.y = fmaf(xv.w, wv.y, a3.y);
        a3.z = fmaf(xv.w, wv.z, a3.z); a3.w = fmaf(xv.w, wv.w, a3.w);
    }
    int jb = tj * 4;
    {
        int g = nb0 + tn * 4;
        if (g < N_NODES) {
            float s = dl[tn * 4];
            unsigned lo = f2bf(a0.x * s) | (f2bf(a0.y * s) << 16);
            unsigned hi = f2bf(a0.z * s) | (f2bf(a0.w * s) << 16);
            *(uint2*)(y + (size_t)g * D + jb) = make_uint2(lo, hi);
        }
    }
    {
        int g = nb0 + tn * 4 + 1;
        if (g < N_NODES) {
            float s = dl[tn * 4 + 1];
            unsigned lo = f2bf(a1.x * s) | (f2bf(a1.y * s) << 16);
            unsigned hi = f2bf(a1.z * s) | (f2bf(a1.w * s) << 16);
            *(uint2*)(y + (size_t)g * D + jb) = make_uint2(lo, hi);
        }
    }
    {
        int g = nb0 + tn * 4 + 2;
        if (g < N_NODES) {
            float s = dl[tn * 4 + 2];
            unsigned lo = f2bf(a2.x * s) | (f2bf(a2.y * s) << 16);
            unsigned hi = f2bf(a2.z * s) | (f2bf(a2.w * s) << 16);
            *(uint2*)(y + (size_t)g * D + jb) = make_uint2(lo, hi);
        }
    }
    {
        int g = nb0 + tn * 4 + 3;
        if (g < N_NODES) {
            float s = dl[tn * 4 + 3];
            unsigned lo = f2bf(a3.x * s) | (f2bf(a3.y * s) << 16);
            unsigned hi = f2bf(a3.z * s) | (f2bf(a3.w * s) << 16);
            *(uint2*)(y + (size_t)g * D + jb) = make_uint2(lo, hi);
        }
    }
}

// Per-bucket: LDS hist -> scan -> fine-bin -> per-wave gather + bias + relu.
// dinv recomputed locally from hist (no global dinv array).
__global__ __launch_bounds__(256) void mega_kernel(
        const int* __restrict__ pairs, const int* __restrict__ bcur,
        const unsigned short* __restrict__ y,
        const float* __restrict__ bias, float* __restrict__ out) {
    __shared__ int hist[BNODES];
    __shared__ int sc[BNODES];
    __shared__ int lrptr[BNODES + 1];
    __shared__ int lcur[BNODES];
    __shared__ float dl[BNODES];
    __shared__ int lds_scol[CAP];
    int t = threadIdx.x;
    int b = blockIdx.x;
    int beg = b * CAP, end = bcur[b];
    if (t < BNODES) hist[t] = 0;
    __syncthreads();
    for (int k = beg + t; k < end; k += 256)
        atomicAdd(&hist[pairs[k] >> COLBITS], 1);
    __syncthreads();
    if (t < BNODES) sc[t] = hist[t];
    __syncthreads();
    for (int off = 1; off < BNODES; off <<= 1) {
        int v = (t < BNODES && t >= off) ? sc[t - off] : 0;
        __syncthreads();
        if (t < BNODES) sc[t] += v;
        __syncthreads();
    }
    if (t < BNODES) {
        lrptr[t + 1] = sc[t];
        lcur[t] = sc[t] - hist[t];
        dl[t] = (hist[t] > 0) ? rsqrtf((float)hist[t]) : 0.0f;
    }
    if (t == 0) lrptr[0] = 0;
    __syncthreads();
    for (int k = beg + t; k < end; k += 256) {
        int p = pairs[k];
        int pos = atomicAdd(&lcur[p >> COLBITS], 1);
        lds_scol[pos] = p & COLMASK;
    }
    __syncthreads();
    int wave = t >> 6, j = t & 63;
    float bj = bias[j];
    for (int ln = wave; ln < BNODES; ln += 4) {
        int n = (b << BSHIFT) + ln;
        if (n >= N_NODES) break;   // only trips in the tail bucket
        int s = lrptr[ln], e2 = lrptr[ln + 1];
        float a0 = 0, a1 = 0, a2 = 0, a3 = 0, a4 = 0, a5 = 0, a6 = 0, a7 = 0;
        int k = s;
        for (; k + 7 < e2; k += 8) {
            int c0 = lds_scol[k + 0], c1 = lds_scol[k + 1];
            int c2 = lds_scol[k + 2], c3 = lds_scol[k + 3];
            int c4 = lds_scol[k + 4], c5 = lds_scol[k + 5];
            int c6 = lds_scol[k + 6], c7 = lds_scol[k + 7];
            a0 += bf2f(y[(size_t)c0 * D + j]);
            a1 += bf2f(y[(size_t)c1 * D + j]);
            a2 += bf2f(y[(size_t)c2 * D + j]);
            a3 += bf2f(y[(size_t)c3 * D + j]);
            a4 += bf2f(y[(size_t)c4 * D + j]);
            a5 += bf2f(y[(size_t)c5 * D + j]);
            a6 += bf2f(y[(size_t)c6 * D + j]);
            a7 += bf2f(y[(size_t)c7 * D + j]);
        }
        for (; k < e2; ++k) a0 += bf2f(y[(size_t)lds_scol[k] * D + j]);
        float sum = ((a0 + a1) + (a2 + a3)) + ((a4 + a5) + (a6 + a7));
        out[(size_t)n * D + j] = fmaxf(fmaf(dl[ln], sum, bj), 0.0f);
    }
}

extern "C" void kernel_launch(void* const* d_in, const int* in_sizes, int n_in,
                              void* d_out, int out_size, void* d_ws, size_t ws_size,
                              hipStream_t stream) {
    const float* x    = (const float*)d_in[0];
    const int*   eidx = (const int*)d_in[1];
    const float* W    = (const float*)d_in[2];
    const float* b    = (const float*)d_in[3];
    float* out = (float*)d_out;
    char* ws = (char*)d_ws;

    const int* row = eidx;
    const int* col = eidx + N_EDGES;

    int* bcur  = (int*)(ws + BCUR_OFF);
    int* pairs = (int*)(ws + PAIRS_OFF);
    unsigned short* y = (unsigned short*)(ws + Y_OFF);

    initcur_kernel<<<(NBUCKET + 255) / 256, 256, 0, stream>>>(bcur);
    scat_kernel<<<NCHUNK, 256, 0, stream>>>(row, col, bcur, pairs);
    xform_kernel<<<NBUCKET, 256, 0, stream>>>(x, W, pairs, bcur, y);
    mega_kernel<<<NBUCKET, 256, 0, stream>>>(pairs, bcur, y, b, out);
}